// Round 19
// baseline (10060.439 us; speedup 1.0000x reference)
//
#include <hip/hip_runtime.h>
#include <hip/hip_bf16.h>

typedef unsigned int uint;
typedef unsigned short ushort;
typedef __fp16 half2_t __attribute__((ext_vector_type(2)));

// ---------- helpers ----------
__device__ __forceinline__ ushort f16b(float x){
  return __builtin_bit_cast(ushort, (_Float16)x);   // RNE
}
__device__ __forceinline__ uint pk_rne(float a, float b){
  return (uint)f16b(a) | ((uint)f16b(b) << 16);
}
// hi/lo double-f16 split; lo scaled by 2^11 (stays f16-normal; avoids dot2 FTZ).
// value = hi + lo * 2^-11
__device__ __forceinline__ void pk_hl(float a, float b, uint& h, uint& l){
  _Float16 ha = (_Float16)a, hb = (_Float16)b;      // RNE
  float la = (a - (float)ha) * 2048.f;
  float lb = (b - (float)hb) * 2048.f;
  h = (uint)__builtin_bit_cast(ushort, ha) | ((uint)__builtin_bit_cast(ushort, hb) << 16);
  l = pk_rne(la, lb);
}
__device__ __forceinline__ float fdot2(uint a, uint b, float c){
#if __has_builtin(__builtin_amdgcn_fdot2)
  return __builtin_amdgcn_fdot2(__builtin_bit_cast(half2_t, a),
                                __builtin_bit_cast(half2_t, b), c, false);
#else
  half2_t ha = __builtin_bit_cast(half2_t, a), hb = __builtin_bit_cast(half2_t, b);
  return c + (float)ha.x*(float)hb.x + (float)ha.y*(float)hb.y;
#endif
}
__device__ __forceinline__ float sigm(float x){ return 1.0f/(1.0f+__expf(-x)); }
__device__ __forceinline__ float tanh_(float x){
  x = fminf(fmaxf(x, -15.f), 15.f);
  float e = __expf(-2.f*x);
  return (1.f-e)/(1.f+e);
}
#define LO_SCALE (1.0f/2048.0f)

// B=128, C=8, N=256, T=64, Hd=256, L=2, F=32 ; OUTPUT = float32

// ---------- kPack ----------
// Wd4   [128 kpp][256 o] uint4 {hi,lo,hi,lo}  k=[xi|attn]
// Wc4hi [256 kp][256 h]  uint4 gate-hi ; Wc4lo gate-lo.  k=[xd|ht]
// Wl24  [136 kpp][256 o] uint4 like Wd4       k=relu([ct|ht|v]) (544)
// Wl1f [512][32] f32 ; WcrotF [64 rb][64 s][32 f] f32 (ring-rotated) ; WhT2 [128][256]
__global__ void kPack(const float* __restrict__ Wd, const float* __restrict__ Wih,
                      const float* __restrict__ Whh, const float* __restrict__ Wl1,
                      const float* __restrict__ Wl2, const float* __restrict__ Wc,
                      const float* __restrict__ Wh,  const float* __restrict__ bih,
                      const float* __restrict__ bhh,
                      uint4* __restrict__ Wd4, uint4* __restrict__ Wc4hi,
                      uint4* __restrict__ Wc4lo, uint4* __restrict__ Wl24,
                      float* __restrict__ Wl1f, float* __restrict__ WcrotF,
                      uint* __restrict__ WhT2, float* __restrict__ bcomb)
{
  const int NTOT = 32768 + 65536 + 34816 + 16384 + 131072 + 32768 + 1024;
  for (int idx = blockIdx.x*blockDim.x + threadIdx.x; idx < NTOT; idx += gridDim.x*blockDim.x){
    int i = idx;
    if (i < 32768){
      int kpp=i>>8, o=i&255, k0=4*kpp;
      uint h0,l0,h1,l1;
      pk_hl(Wd[o*512+k0],   Wd[o*512+k0+1], h0,l0);
      pk_hl(Wd[o*512+k0+2], Wd[o*512+k0+3], h1,l1);
      Wd4[i] = make_uint4(h0,l0,h1,l1); continue; }
    i -= 32768;
    if (i < 65536){
      int kp=i>>8, hh=i&255;
      uint wh[4], wl[4];
      #pragma unroll
      for (int gi=0; gi<4; gi++){
        int row = gi*256+hh;
        float a,b;
        if (kp<128){ a=Wih[row*256+2*kp]; b=Wih[row*256+2*kp+1]; }
        else       { a=Whh[row*256+2*(kp-128)]; b=Whh[row*256+2*(kp-128)+1]; }
        pk_hl(a,b,wh[gi],wl[gi]);
      }
      Wc4hi[i] = make_uint4(wh[0],wh[1],wh[2],wh[3]);
      Wc4lo[i] = make_uint4(wl[0],wl[1],wl[2],wl[3]); continue; }
    i -= 65536;
    if (i < 34816){
      int kpp=i>>8, o=i&255, k0=4*kpp;
      uint h0,l0,h1,l1;
      pk_hl(Wl2[o*544+k0],   Wl2[o*544+k0+1], h0,l0);
      pk_hl(Wl2[o*544+k0+2], Wl2[o*544+k0+3], h1,l1);
      Wl24[i] = make_uint4(h0,l0,h1,l1); continue; }
    i -= 34816;
    if (i < 16384){ int kk=i>>5, f=i&31; Wl1f[i] = Wl1[f*512+kk]; continue; }
    i -= 16384;
    if (i < 131072){ int rb=i>>11, r=i&2047, s=r>>5, f=r&31;
      WcrotF[i] = Wc[f*64 + ((s - rb) & 63)]; continue; }
    i -= 131072;
    if (i < 32768){ int np=i>>8, h=i&255;
      WhT2[i] = pk_rne(Wh[h*256+2*np], Wh[h*256+2*np+1]); continue; }
    i -= 32768;
    bcomb[i] = bih[i] + bhh[i];
  }
}

// ---------- K1a ----------
__global__ void k1a(const float* __restrict__ x, const float* __restrict__ wst,
                    const float* __restrict__ bst, ushort* __restrict__ yT)
{
  int b = blockIdx.x, tq = blockIdx.y, n = threadIdx.x;
  float acc[16];
  #pragma unroll
  for (int k=0;k<16;k++) acc[k]=0.f;
  for (int c=0;c<8;c++){
    const float4* xp = (const float4*)(x + ((size_t)((b*8+c)*256 + n)*64 + tq*16));
    float wc = wst[c];
    #pragma unroll
    for (int q=0;q<4;q++){
      float4 v = xp[q];
      acc[4*q+0] += v.x*wc; acc[4*q+1] += v.y*wc;
      acc[4*q+2] += v.z*wc; acc[4*q+3] += v.w*wc;
    }
  }
  float b0 = bst[0];
  #pragma unroll
  for (int k=0;k<16;k++){
    float v = fmaxf(acc[k]+b0, 0.f);
    yT[(size_t)(b*64 + tq*16 + k)*256 + n] = f16b(v);
  }
}

// ---------- K1b ----------
__global__ void k1b(const uint* __restrict__ yT2, const uint* __restrict__ WhT2,
                    const float* __restrict__ bh, float* __restrict__ xcon)
{
  __shared__ uint yp[8192];
  int b = blockIdx.x, tid = threadIdx.x;
  for (int i = tid; i < 8192; i += 256) yp[i] = yT2[(size_t)b*8192 + i];
  __syncthreads();
  int h = tid;
  float bias = bh[h];
  for (int tq=0;tq<4;tq++){
    float acc[16];
    #pragma unroll
    for (int k=0;k<16;k++) acc[k]=0.f;
    for (int np=0;np<128;np++){
      uint w2 = WhT2[np*256 + h];
      #pragma unroll
      for (int k=0;k<16;k++)
        acc[k] = fdot2(yp[(tq*16+k)*128 + np], w2, acc[k]);
    }
    #pragma unroll
    for (int k=0;k<16;k++)
      xcon[(size_t)(b*64 + tq*16 + k)*256 + h] = fmaxf(acc[k]+bias, 0.f);
  }
}

// ---------- K2: scan — 1024 threads, 4-way k-split, exact-f32 attention ----------
__global__ __launch_bounds__(1024, 1)
void TPALSTM_17205638987874_kernel(const float* __restrict__ xcon,
        const uint4* __restrict__ Wd4, const uint4* __restrict__ Wc4hi,
        const uint4* __restrict__ Wc4lo, const uint4* __restrict__ Wl24,
        const float* __restrict__ Wl1f, const float* __restrict__ WcrotF,
        const float* __restrict__ bd, const float* __restrict__ bcomb,
        const float* __restrict__ bl1, const float* __restrict__ bl2,
        const float* __restrict__ bc, float* __restrict__ res)
{
  __shared__ float Hf32[64][256];          // Hbuf ring, f32 (phys slot s = base&63)
  __shared__ float cvs[256][33];           // cv f32 [o][f] (+1 pad)
  __shared__ float gp[16][256];            // gate partials
  __shared__ float p4[4][256];             // 4-way GEMV partials
  __shared__ float ht[256], ct[256], alpha[256];  // alpha doubles as nh-stash
  __shared__ __align__(16) uint2 APR2[288];// {hi, lo_scaled} per k-pair
  __shared__ float wv[32];                 // wl1 result, f32

  int b = blockIdx.x, tid = threadIdx.x;
  int g = tid >> 8, o = tid & 255;
  int gu = __builtin_amdgcn_readfirstlane(g);   // wave-uniform group id (SGPR)

  // ---- loop-invariant first-weights prefetch (hides L2 latency at phase start;
  //      streams restart at the same base every iteration) ----
  const uint4* s2base = Wd4  + (size_t)(g*32)*256 + o;   // shared by S2 and S14
  const uint4* s4hb   = Wc4hi + (size_t)(g*64)*256 + o;
  const uint4* s4lb   = Wc4lo + (size_t)(g*64)*256 + o;
  const uint4* s12b   = Wl24 + (size_t)(g*34)*256 + o;
  uint4 pw0 = s2base[0],  pw1 = s2base[256];
  uint4 ph0 = s4hb[0],    ph1 = s4hb[256];
  uint4 pl0 = s4lb[0],    pl1 = s4lb[256];
  uint4 pq0 = s12b[0],    pq1 = s12b[256];

  for (int i = tid; i < 64*256; i += 1024) ((float*)Hf32)[i] = 0.f;
  if (tid < 256){ ht[tid]=0.f; ct[tid]=0.f; }
  if (tid >= 128 && tid < 256) APR2[tid] = make_uint2(0u,0u);  // attn_out = 0
  if (tid < 128){                                              // t=0 xi
    const float* xr = xcon + (size_t)(b*64+0)*256;
    uint h,l; pk_hl(xr[2*tid], xr[2*tid+1], h, l);
    APR2[tid] = make_uint2(h,l);
  }
  __syncthreads();

  int base = 0;
  for (int t=0;t<64;t++){
    for (int l=0;l<2;l++){
      // S2: xd partials  (g: kpp in [g*32, g*32+32)), first 2 kpp peeled from regs
      {
        float ahi=0.f, alo=0.f;
        const uint4* ap = (const uint4*)(APR2 + g*64);
        uint4 A0 = ap[0], A1 = ap[1];
        ahi = fdot2(A0.x, pw0.x, ahi); alo = fdot2(A0.y, pw0.x, alo); alo = fdot2(A0.x, pw0.y, alo);
        ahi = fdot2(A0.z, pw0.z, ahi); alo = fdot2(A0.w, pw0.z, alo); alo = fdot2(A0.z, pw0.w, alo);
        ahi = fdot2(A1.x, pw1.x, ahi); alo = fdot2(A1.y, pw1.x, alo); alo = fdot2(A1.x, pw1.y, alo);
        ahi = fdot2(A1.z, pw1.z, ahi); alo = fdot2(A1.w, pw1.z, alo); alo = fdot2(A1.z, pw1.w, alo);
        const uint4* wp = s2base + 512;
        #pragma unroll 4
        for (int kpp=2;kpp<32;kpp++){
          uint4 w = wp[0]; wp += 256;
          uint4 A = ap[kpp];
          ahi = fdot2(A.x, w.x, ahi); alo = fdot2(A.y, w.x, alo); alo = fdot2(A.x, w.y, alo);
          ahi = fdot2(A.z, w.z, ahi); alo = fdot2(A.w, w.z, alo); alo = fdot2(A.z, w.w, alo);
        }
        p4[g][o] = ahi + alo*LO_SCALE;
      }
      __syncthreads();
      // S3: APR = [xd | ht raw]
      if (tid < 128){
        int o0=2*tid, o1=o0+1;
        float x0 = p4[0][o0]+p4[1][o0]+p4[2][o0]+p4[3][o0]+bd[o0];
        float x1 = p4[0][o1]+p4[1][o1]+p4[2][o1]+p4[3][o1]+bd[o1];
        uint h,l; pk_hl(x0,x1,h,l); APR2[tid]=make_uint2(h,l);
      } else if (tid < 256){
        int j=tid-128; uint h,l; pk_hl(ht[2*j], ht[2*j+1], h, l); APR2[tid]=make_uint2(h,l);
      }
      __syncthreads();
      // S4: gate partials  (g: kp in [g*64, g*64+64)), first 2 kp peeled
      {
        float ih=0.f,il=0.f,fh=0.f,fl=0.f,gh=0.f,gl=0.f,oh=0.f,ol=0.f;
        {
          uint2 A = APR2[g*64];
          ih=fdot2(A.x,ph0.x,ih); il=fdot2(A.y,ph0.x,il); il=fdot2(A.x,pl0.x,il);
          fh=fdot2(A.x,ph0.y,fh); fl=fdot2(A.y,ph0.y,fl); fl=fdot2(A.x,pl0.y,fl);
          gh=fdot2(A.x,ph0.z,gh); gl=fdot2(A.y,ph0.z,gl); gl=fdot2(A.x,pl0.z,gl);
          oh=fdot2(A.x,ph0.w,oh); ol=fdot2(A.y,ph0.w,ol); ol=fdot2(A.x,pl0.w,ol);
        }
        {
          uint2 A = APR2[g*64+1];
          ih=fdot2(A.x,ph1.x,ih); il=fdot2(A.y,ph1.x,il); il=fdot2(A.x,pl1.x,il);
          fh=fdot2(A.x,ph1.y,fh); fl=fdot2(A.y,ph1.y,fl); fl=fdot2(A.x,pl1.y,fl);
          gh=fdot2(A.x,ph1.z,gh); gl=fdot2(A.y,ph1.z,gl); gl=fdot2(A.x,pl1.z,gl);
          oh=fdot2(A.x,ph1.w,oh); ol=fdot2(A.y,ph1.w,ol); ol=fdot2(A.x,pl1.w,ol);
        }
        const uint4* whp = s4hb + 512;
        const uint4* wlp = s4lb + 512;
        #pragma unroll 4
        for (int kp=g*64+2; kp<g*64+64; kp++){
          uint4 w = whp[0]; whp += 256;
          uint4 v = wlp[0]; wlp += 256;
          uint2 A = APR2[kp];
          ih=fdot2(A.x,w.x,ih); il=fdot2(A.y,w.x,il); il=fdot2(A.x,v.x,il);
          fh=fdot2(A.x,w.y,fh); fl=fdot2(A.y,w.y,fl); fl=fdot2(A.x,v.y,fl);
          gh=fdot2(A.x,w.z,gh); gl=fdot2(A.y,w.z,gl); gl=fdot2(A.x,v.z,gl);
          oh=fdot2(A.x,w.w,oh); ol=fdot2(A.y,w.w,ol); ol=fdot2(A.x,v.w,ol);
        }
        gp[g*4+0][o]=ih+il*LO_SCALE; gp[g*4+1][o]=fh+fl*LO_SCALE;
        gp[g*4+2][o]=gh+gl*LO_SCALE; gp[g*4+3][o]=oh+ol*LO_SCALE;
      }
      __syncthreads();
      // cell (g==0 threads, h = o)
      if (g==0){
        float gi = sigm (gp[0][o]+gp[4][o]+gp[8][o] +gp[12][o]+bcomb[o]);
        float gf = sigm (gp[1][o]+gp[5][o]+gp[9][o] +gp[13][o]+bcomb[256+o]);
        float gg = tanh_(gp[2][o]+gp[6][o]+gp[10][o]+gp[14][o]+bcomb[512+o]);
        float go = sigm (gp[3][o]+gp[7][o]+gp[11][o]+gp[15][o]+bcomb[768+o]);
        float c2 = gf*ct[o] + gi*gg;
        float h2 = go*tanh_(c2);
        ct[o]=c2; ht[o]=h2;
      }
      __syncthreads();
      // S5+S6: APR=relu([ct|ht]); conv (all g, 8 f each, exact f32); wl1 (g==3, o<64)
      if (tid < 128){ uint h,l; pk_hl(fmaxf(ct[2*tid],0.f), fmaxf(ct[2*tid+1],0.f), h,l); APR2[tid]=make_uint2(h,l); }
      else if (tid < 256){ int j=tid-128; uint h,l; pk_hl(fmaxf(ht[2*j],0.f), fmaxf(ht[2*j+1],0.f), h,l); APR2[tid]=make_uint2(h,l); }
      {
        int rb = base & 63;
        const float4* wp = (const float4*)(WcrotF + rb*2048 + gu*8);
        float a0=0.f,a1=0.f,a2=0.f,a3=0.f,a4=0.f,a5=0.f,a6=0.f,a7=0.f;
        #pragma unroll 4
        for (int s=0;s<64;s++){
          float hv = Hf32[s][o];
          float4 wa = wp[s*8];
          float4 wb = wp[s*8+1];
          a0 += hv*wa.x; a1 += hv*wa.y; a2 += hv*wa.z; a3 += hv*wa.w;
          a4 += hv*wb.x; a5 += hv*wb.y; a6 += hv*wb.z; a7 += hv*wb.w;
        }
        int f0 = gu*8;
        cvs[o][f0+0] = fmaxf(a0+bc[f0+0],0.f); cvs[o][f0+1] = fmaxf(a1+bc[f0+1],0.f);
        cvs[o][f0+2] = fmaxf(a2+bc[f0+2],0.f); cvs[o][f0+3] = fmaxf(a3+bc[f0+3],0.f);
        cvs[o][f0+4] = fmaxf(a4+bc[f0+4],0.f); cvs[o][f0+5] = fmaxf(a5+bc[f0+5],0.f);
        cvs[o][f0+6] = fmaxf(a6+bc[f0+6],0.f); cvs[o][f0+7] = fmaxf(a7+bc[f0+7],0.f);
      }
      if (g==3 && o < 64){
        int f = o & 31, kh = o >> 5;          // 2 threads per f, k-halves
        float a=0.f;
        const float* w = Wl1f + f;
        if (kh==0){ for (int k=0;k<256;k++) a += ct[k]*w[k*32]; }
        else      { for (int k=0;k<256;k++) a += ht[k]*w[(256+k)*32]; }
        a += __shfl_xor(a, 32);               // combine halves
        if (kh==0) wv[f] = a + bl1[f];
      }
      __syncthreads();
      // S8: alpha (f32)
      if (tid < 256){
        float s=0.f;
        #pragma unroll
        for (int f=0;f<32;f++) s += cvs[tid][f]*wv[f];
        alpha[tid] = sigm(s);
      }
      __syncthreads();
      // S9+S10 merged: v via in-wave shuffle tree -> APR[256..271]
      // oa = 4og+(oo&3)+32(oo>>2): bank=(4og+f+(oo&3))&31 -> exact ≤2-way (free)
      if (tid < 256){
        int f = tid>>3, og = tid&7;
        float s=0.f;
        #pragma unroll 8
        for (int oo=0;oo<32;oo++){
          int oa = 4*og + (oo&3) + 32*(oo>>2);
          s += alpha[oa]*cvs[oa][f];
        }
        s += __shfl_xor(s,1); s += __shfl_xor(s,2); s += __shfl_xor(s,4);  // og-reduce
        float vn = __shfl_xor(s,8);            // partner f^1
        if (og==0 && !(f&1)){
          uint h,l; pk_hl(fmaxf(s,0.f), fmaxf(vn,0.f), h,l);
          APR2[256+(f>>1)]=make_uint2(h,l);
        }
      }
      __syncthreads();
      // S12: Wl2 partials  (g: kpp in [g*34, g*34+34)), first 2 peeled
      {
        float ahi=0.f, alo=0.f;
        const uint4* ap = (const uint4*)(APR2 + g*68);
        uint4 A0 = ap[0], A1 = ap[1];
        ahi = fdot2(A0.x, pq0.x, ahi); alo = fdot2(A0.y, pq0.x, alo); alo = fdot2(A0.x, pq0.y, alo);
        ahi = fdot2(A0.z, pq0.z, ahi); alo = fdot2(A0.w, pq0.z, alo); alo = fdot2(A0.z, pq0.w, alo);
        ahi = fdot2(A1.x, pq1.x, ahi); alo = fdot2(A1.y, pq1.x, alo); alo = fdot2(A1.x, pq1.y, alo);
        ahi = fdot2(A1.z, pq1.z, ahi); alo = fdot2(A1.w, pq1.z, alo); alo = fdot2(A1.z, pq1.w, alo);
        const uint4* wp = s12b + 512;
        #pragma unroll 4
        for (int kpp=2;kpp<34;kpp++){
          uint4 w = wp[0]; wp += 256;
          uint4 A = ap[kpp];
          ahi = fdot2(A.x, w.x, ahi); alo = fdot2(A.y, w.x, alo); alo = fdot2(A.x, w.y, alo);
          ahi = fdot2(A.z, w.z, ahi); alo = fdot2(A.w, w.z, alo); alo = fdot2(A.z, w.w, alo);
        }
        p4[g][o] = ahi + alo*LO_SCALE;
      }
      __syncthreads();
      // S13: APR = [ht raw | nh]; stash nh in alpha[] (dead until next S8)
      if (tid<128){ uint h,l; pk_hl(ht[2*tid], ht[2*tid+1], h,l); APR2[tid]=make_uint2(h,l); }
      else if (tid<256){
        int j=tid-128, o0=2*j, o1=o0+1;
        float n0 = p4[0][o0]+p4[1][o0]+p4[2][o0]+p4[3][o0]+bl2[o0];
        float n1 = p4[0][o1]+p4[1][o1]+p4[2][o1]+p4[3][o1]+bl2[o1];
        uint h,l; pk_hl(n0,n1,h,l); APR2[tid]=make_uint2(h,l);
        alpha[o0] = n0; alpha[o1] = n1;       // nh stash
      }
      __syncthreads();
      // res write (alpha stash) ∥ S14: output partials (Wd4 stream, peeled regs)
      if (l==1 && tid>=128 && tid<256){
        int j=tid-128, o0=2*j, o1=o0+1;
        float* rr = res + (size_t)(t*128+b)*256;
        rr[o0] = alpha[o0]; rr[o1] = alpha[o1];
      }
      {
        float ahi=0.f, alo=0.f;
        const uint4* ap = (const uint4*)(APR2 + g*64);
        uint4 A0 = ap[0], A1 = ap[1];
        ahi = fdot2(A0.x, pw0.x, ahi); alo = fdot2(A0.y, pw0.x, alo); alo = fdot2(A0.x, pw0.y, alo);
        ahi = fdot2(A0.z, pw0.z, ahi); alo = fdot2(A0.w, pw0.z, alo); alo = fdot2(A0.z, pw0.w, alo);
        ahi = fdot2(A1.x, pw1.x, ahi); alo = fdot2(A1.y, pw1.x, alo); alo = fdot2(A1.x, pw1.y, alo);
        ahi = fdot2(A1.z, pw1.z, ahi); alo = fdot2(A1.w, pw1.z, alo); alo = fdot2(A1.z, pw1.w, alo);
        const uint4* wp = s2base + 512;
        #pragma unroll 4
        for (int kpp=2;kpp<32;kpp++){
          uint4 w = wp[0]; wp += 256;
          uint4 A = ap[kpp];
          ahi = fdot2(A.x, w.x, ahi); alo = fdot2(A.y, w.x, alo); alo = fdot2(A.x, w.y, alo);
          ahi = fdot2(A.z, w.z, ahi); alo = fdot2(A.w, w.z, alo); alo = fdot2(A.z, w.w, alo);
        }
        p4[g][o] = ahi + alo*LO_SCALE;
      }
      __syncthreads();
      // S15: Hbuf ring append relu(output) f32; next xi (output for l=0, xcon[t+1] for l=1)
      if (tid<128){
        int o0=2*tid, o1=o0+1;
        float u0 = p4[0][o0]+p4[1][o0]+p4[2][o0]+p4[3][o0]+bd[o0];
        float u1 = p4[0][o1]+p4[1][o1]+p4[2][o1]+p4[3][o1]+bd[o1];
        int s = base & 63;
        Hf32[s][o0] = fmaxf(u0,0.f);
        Hf32[s][o1] = fmaxf(u1,0.f);
        if (l==0){
          uint h,lw; pk_hl(u0, u1, h, lw);
          APR2[tid]=make_uint2(h,lw);
        } else if (t < 63){
          const float* xr = xcon + (size_t)(b*64+t+1)*256;
          uint h,lw; pk_hl(xr[o0], xr[o1], h, lw);
          APR2[tid]=make_uint2(h,lw);
        }
      }
      __syncthreads();
      base++;
    }
  }
}

// ---------- K3: out[b,c,h,t] = relu(res[t,b,h])*wend[c] + bend[c]  (float32) ----------
__global__ void k3(const float* __restrict__ res, const float* __restrict__ wend,
                   const float* __restrict__ bend, float* __restrict__ out)
{
  __shared__ float r2[64][257];
  int b = blockIdx.x, tid = threadIdx.x;
  for (int i = tid; i < 16384; i += 256){
    int t = i >> 8, h = i & 255;
    r2[t][h] = fmaxf(res[(size_t)(t*128+b)*256 + h], 0.f);
  }
  __syncthreads();
  int tt = tid & 63, hg = tid >> 6;
  for (int c=0;c<8;c++){
    float we = wend[c], be = bend[c];
    for (int hh=0;hh<64;hh++){
      int h = hg*64 + hh;
      out[((size_t)(b*8+c)*256 + h)*64 + tt] = r2[tt][h]*we + be;
    }
  }
}

// ---------- launch ----------
extern "C" __attribute__((visibility("default"), used))
void kernel_launch(void* const* d_in, const int* in_sizes, int n_in,
                   void* d_out, int out_size, void* d_ws, size_t ws_size,
                   hipStream_t stream)
{
  const float* x    = (const float*)d_in[0];
  const float* wst  = (const float*)d_in[1];
  const float* bst  = (const float*)d_in[2];
  const float* Wh   = (const float*)d_in[3];
  const float* bh   = (const float*)d_in[4];
  const float* Wih  = (const float*)d_in[5];
  const float* Whh  = (const float*)d_in[6];
  const float* bih  = (const float*)d_in[7];
  const float* bhh  = (const float*)d_in[8];
  const float* Wd   = (const float*)d_in[9];
  const float* bd   = (const float*)d_in[10];
  const float* Wc   = (const float*)d_in[11];
  const float* bc   = (const float*)d_in[12];
  const float* Wl1  = (const float*)d_in[13];
  const float* bl1  = (const float*)d_in[14];
  const float* Wl2  = (const float*)d_in[15];
  const float* bl2  = (const float*)d_in[16];
  const float* wend = (const float*)d_in[17];
  const float* bend = (const float*)d_in[18];

  char* ws = (char*)d_ws;
  uint4* Wd4    = (uint4*)(ws + 0);          // 524288 B
  uint4* Wc4hi  = (uint4*)(ws + 524288);     // 1048576 B
  uint4* Wc4lo  = (uint4*)(ws + 1572864);    // 1048576 B
  uint4* Wl24   = (uint4*)(ws + 2621440);    // 557056 B
  float* Wl1f   = (float*)(ws + 3178496);    // 65536 B
  float* WcrotF = (float*)(ws + 3244032);    // 524288 B
  uint*  WhT2   = (uint*) (ws + 3768320);    // 131072 B
  float* bcomb  = (float*)(ws + 3899392);    // 4096 B
  ushort* yT    = (ushort*)(ws + 3903488);   // 4194304 B
  float* xcon   = (float*)(ws + 8097792);    // 8388608 B
  float* res    = (float*)(ws + 16486400);   // 8388608 B -> end 24875008

  kPack<<<512, 256, 0, stream>>>(Wd, Wih, Whh, Wl1, Wl2, Wc, Wh, bih, bhh,
                                 Wd4, Wc4hi, Wc4lo, Wl24, Wl1f, WcrotF, WhT2, bcomb);
  k1a<<<dim3(128,4), 256, 0, stream>>>(x, wst, bst, yT);
  k1b<<<128, 256, 0, stream>>>((const uint*)yT, WhT2, bh, xcon);
  TPALSTM_17205638987874_kernel<<<128, 1024, 0, stream>>>(xcon, Wd4, Wc4hi, Wc4lo, Wl24,
                                                          Wl1f, WcrotF,
                                                          bd, bcomb, bl1, bl2, bc, res);
  k3<<<128, 256, 0, stream>>>(res, wend, bend, (float*)d_out);
}

// Round 20
// 4890.792 us; speedup vs baseline: 2.0570x; 2.0570x over previous
//
#include <hip/hip_runtime.h>
#include <hip/hip_bf16.h>

typedef unsigned int uint;
typedef unsigned short ushort;
typedef __fp16 half2_t __attribute__((ext_vector_type(2)));

// ---------- helpers ----------
__device__ __forceinline__ ushort f16b(float x){
  return __builtin_bit_cast(ushort, (_Float16)x);   // RNE
}
__device__ __forceinline__ uint pk_rne(float a, float b){
  return (uint)f16b(a) | ((uint)f16b(b) << 16);
}
// hi/lo double-f16 split; lo scaled by 2^11 (stays f16-normal; avoids dot2 FTZ).
// value = hi + lo * 2^-11
__device__ __forceinline__ void pk_hl(float a, float b, uint& h, uint& l){
  _Float16 ha = (_Float16)a, hb = (_Float16)b;      // RNE
  float la = (a - (float)ha) * 2048.f;
  float lb = (b - (float)hb) * 2048.f;
  h = (uint)__builtin_bit_cast(ushort, ha) | ((uint)__builtin_bit_cast(ushort, hb) << 16);
  l = pk_rne(la, lb);
}
__device__ __forceinline__ float fdot2(uint a, uint b, float c){
#if __has_builtin(__builtin_amdgcn_fdot2)
  return __builtin_amdgcn_fdot2(__builtin_bit_cast(half2_t, a),
                                __builtin_bit_cast(half2_t, b), c, false);
#else
  half2_t ha = __builtin_bit_cast(half2_t, a), hb = __builtin_bit_cast(half2_t, b);
  return c + (float)ha.x*(float)hb.x + (float)ha.y*(float)hb.y;
#endif
}
__device__ __forceinline__ float sigm(float x){ return 1.0f/(1.0f+__expf(-x)); }
__device__ __forceinline__ float tanh_(float x){
  x = fminf(fmaxf(x, -15.f), 15.f);
  float e = __expf(-2.f*x);
  return (1.f-e)/(1.f+e);
}
#define LO_SCALE (1.0f/2048.0f)

// B=128, C=8, N=256, T=64, Hd=256, L=2, F=32 ; OUTPUT = float32

// ---------- kPack ----------
// Wd4   [128 kpp][256 o] uint4 {hi,lo,hi,lo}  k=[xi|attn]
// Wc4hi [256 kp][256 h]  uint4 gate-hi ; Wc4lo gate-lo.  k=[xd|ht]
// Wl24  [136 kpp][256 o] uint4 like Wd4       k=relu([ct|ht|v]) (544)
// Wl1f [512][32] f32 ; WcrotF [64 rb][64 s][32 f] f32 (ring-rotated) ; WhT2 [128][256]
__global__ void kPack(const float* __restrict__ Wd, const float* __restrict__ Wih,
                      const float* __restrict__ Whh, const float* __restrict__ Wl1,
                      const float* __restrict__ Wl2, const float* __restrict__ Wc,
                      const float* __restrict__ Wh,  const float* __restrict__ bih,
                      const float* __restrict__ bhh,
                      uint4* __restrict__ Wd4, uint4* __restrict__ Wc4hi,
                      uint4* __restrict__ Wc4lo, uint4* __restrict__ Wl24,
                      float* __restrict__ Wl1f, float* __restrict__ WcrotF,
                      uint* __restrict__ WhT2, float* __restrict__ bcomb)
{
  const int NTOT = 32768 + 65536 + 34816 + 16384 + 131072 + 32768 + 1024;
  for (int idx = blockIdx.x*blockDim.x + threadIdx.x; idx < NTOT; idx += gridDim.x*blockDim.x){
    int i = idx;
    if (i < 32768){
      int kpp=i>>8, o=i&255, k0=4*kpp;
      uint h0,l0,h1,l1;
      pk_hl(Wd[o*512+k0],   Wd[o*512+k0+1], h0,l0);
      pk_hl(Wd[o*512+k0+2], Wd[o*512+k0+3], h1,l1);
      Wd4[i] = make_uint4(h0,l0,h1,l1); continue; }
    i -= 32768;
    if (i < 65536){
      int kp=i>>8, hh=i&255;
      uint wh[4], wl[4];
      #pragma unroll
      for (int gi=0; gi<4; gi++){
        int row = gi*256+hh;
        float a,b;
        if (kp<128){ a=Wih[row*256+2*kp]; b=Wih[row*256+2*kp+1]; }
        else       { a=Whh[row*256+2*(kp-128)]; b=Whh[row*256+2*(kp-128)+1]; }
        pk_hl(a,b,wh[gi],wl[gi]);
      }
      Wc4hi[i] = make_uint4(wh[0],wh[1],wh[2],wh[3]);
      Wc4lo[i] = make_uint4(wl[0],wl[1],wl[2],wl[3]); continue; }
    i -= 65536;
    if (i < 34816){
      int kpp=i>>8, o=i&255, k0=4*kpp;
      uint h0,l0,h1,l1;
      pk_hl(Wl2[o*544+k0],   Wl2[o*544+k0+1], h0,l0);
      pk_hl(Wl2[o*544+k0+2], Wl2[o*544+k0+3], h1,l1);
      Wl24[i] = make_uint4(h0,l0,h1,l1); continue; }
    i -= 34816;
    if (i < 16384){ int kk=i>>5, f=i&31; Wl1f[i] = Wl1[f*512+kk]; continue; }
    i -= 16384;
    if (i < 131072){ int rb=i>>11, r=i&2047, s=r>>5, f=r&31;
      WcrotF[i] = Wc[f*64 + ((s - rb) & 63)]; continue; }
    i -= 131072;
    if (i < 32768){ int np=i>>8, h=i&255;
      WhT2[i] = pk_rne(Wh[h*256+2*np], Wh[h*256+2*np+1]); continue; }
    i -= 32768;
    bcomb[i] = bih[i] + bhh[i];
  }
}

// ---------- K1a ----------
__global__ void k1a(const float* __restrict__ x, const float* __restrict__ wst,
                    const float* __restrict__ bst, ushort* __restrict__ yT)
{
  int b = blockIdx.x, tq = blockIdx.y, n = threadIdx.x;
  float acc[16];
  #pragma unroll
  for (int k=0;k<16;k++) acc[k]=0.f;
  for (int c=0;c<8;c++){
    const float4* xp = (const float4*)(x + ((size_t)((b*8+c)*256 + n)*64 + tq*16));
    float wc = wst[c];
    #pragma unroll
    for (int q=0;q<4;q++){
      float4 v = xp[q];
      acc[4*q+0] += v.x*wc; acc[4*q+1] += v.y*wc;
      acc[4*q+2] += v.z*wc; acc[4*q+3] += v.w*wc;
    }
  }
  float b0 = bst[0];
  #pragma unroll
  for (int k=0;k<16;k++){
    float v = fmaxf(acc[k]+b0, 0.f);
    yT[(size_t)(b*64 + tq*16 + k)*256 + n] = f16b(v);
  }
}

// ---------- K1b ----------
__global__ void k1b(const uint* __restrict__ yT2, const uint* __restrict__ WhT2,
                    const float* __restrict__ bh, float* __restrict__ xcon)
{
  __shared__ uint yp[8192];
  int b = blockIdx.x, tid = threadIdx.x;
  for (int i = tid; i < 8192; i += 256) yp[i] = yT2[(size_t)b*8192 + i];
  __syncthreads();
  int h = tid;
  float bias = bh[h];
  for (int tq=0;tq<4;tq++){
    float acc[16];
    #pragma unroll
    for (int k=0;k<16;k++) acc[k]=0.f;
    for (int np=0;np<128;np++){
      uint w2 = WhT2[np*256 + h];
      #pragma unroll
      for (int k=0;k<16;k++)
        acc[k] = fdot2(yp[(tq*16+k)*128 + np], w2, acc[k]);
    }
    #pragma unroll
    for (int k=0;k<16;k++)
      xcon[(size_t)(b*64 + tq*16 + k)*256 + h] = fmaxf(acc[k]+bias, 0.f);
  }
}

// ---------- K2: scan — 1024 threads, 4-way k-split, exact-f32 attention ----------
__global__ __launch_bounds__(1024, 1)
void TPALSTM_17205638987874_kernel(const float* __restrict__ xcon,
        const uint4* __restrict__ Wd4, const uint4* __restrict__ Wc4hi,
        const uint4* __restrict__ Wc4lo, const uint4* __restrict__ Wl24,
        const float* __restrict__ Wl1f, const float* __restrict__ WcrotF,
        const float* __restrict__ bd, const float* __restrict__ bcomb,
        const float* __restrict__ bl1, const float* __restrict__ bl2,
        const float* __restrict__ bc, float* __restrict__ res)
{
  __shared__ float Hf32[64][256];          // Hbuf ring, f32 (phys slot s = base&63)
  __shared__ float cvs[256][33];           // cv f32 [o][f] (+1 pad)
  __shared__ float gp[16][256];            // gate partials
  __shared__ float p4[4][256];             // 4-way GEMV partials
  __shared__ float ht[256], ct[256], alpha[256];  // alpha doubles as nh-stash
  __shared__ __align__(16) uint2 APR2[288];// {hi, lo_scaled} per k-pair
  __shared__ float wv[32];                 // wl1 result, f32

  int b = blockIdx.x, tid = threadIdx.x;
  int g = tid >> 8, o = tid & 255;
  int gu = __builtin_amdgcn_readfirstlane(g);   // wave-uniform group id (SGPR)

  for (int i = tid; i < 64*256; i += 1024) ((float*)Hf32)[i] = 0.f;
  if (tid < 256){ ht[tid]=0.f; ct[tid]=0.f; }
  if (tid >= 128 && tid < 256) APR2[tid] = make_uint2(0u,0u);  // attn_out = 0
  if (tid < 128){                                              // t=0 xi
    const float* xr = xcon + (size_t)(b*64+0)*256;
    uint h,l; pk_hl(xr[2*tid], xr[2*tid+1], h, l);
    APR2[tid] = make_uint2(h,l);
  }
  __syncthreads();

  int base = 0;
  for (int t=0;t<64;t++){
    for (int l=0;l<2;l++){
      // S2: xd partials  (g: kpp in [g*32, g*32+32))
      {
        float ahi=0.f, alo=0.f;
        const uint4* wp = Wd4 + (size_t)(g*32)*256 + o;
        const uint4* ap = (const uint4*)(APR2 + g*64);
        #pragma unroll 4
        for (int kpp=0;kpp<32;kpp++){
          uint4 w = wp[0]; wp += 256;
          uint4 A = ap[kpp];
          ahi = fdot2(A.x, w.x, ahi); alo = fdot2(A.y, w.x, alo); alo = fdot2(A.x, w.y, alo);
          ahi = fdot2(A.z, w.z, ahi); alo = fdot2(A.w, w.z, alo); alo = fdot2(A.z, w.w, alo);
        }
        p4[g][o] = ahi + alo*LO_SCALE;
      }
      __syncthreads();
      // S3: APR = [xd | ht raw]
      if (tid < 128){
        int o0=2*tid, o1=o0+1;
        float x0 = p4[0][o0]+p4[1][o0]+p4[2][o0]+p4[3][o0]+bd[o0];
        float x1 = p4[0][o1]+p4[1][o1]+p4[2][o1]+p4[3][o1]+bd[o1];
        uint h,l; pk_hl(x0,x1,h,l); APR2[tid]=make_uint2(h,l);
      } else if (tid < 256){
        int j=tid-128; uint h,l; pk_hl(ht[2*j], ht[2*j+1], h, l); APR2[tid]=make_uint2(h,l);
      }
      __syncthreads();
      // S4: gate partials  (g: kp in [g*64, g*64+64))
      {
        float ih=0.f,il=0.f,fh=0.f,fl=0.f,gh=0.f,gl=0.f,oh=0.f,ol=0.f;
        const uint4* whp = Wc4hi + (size_t)(g*64)*256 + o;
        const uint4* wlp = Wc4lo + (size_t)(g*64)*256 + o;
        #pragma unroll 4
        for (int kp=g*64; kp<g*64+64; kp++){
          uint4 w = whp[0]; whp += 256;
          uint4 v = wlp[0]; wlp += 256;
          uint2 A = APR2[kp];
          ih=fdot2(A.x,w.x,ih); il=fdot2(A.y,w.x,il); il=fdot2(A.x,v.x,il);
          fh=fdot2(A.x,w.y,fh); fl=fdot2(A.y,w.y,fl); fl=fdot2(A.x,v.y,fl);
          gh=fdot2(A.x,w.z,gh); gl=fdot2(A.y,w.z,gl); gl=fdot2(A.x,v.z,gl);
          oh=fdot2(A.x,w.w,oh); ol=fdot2(A.y,w.w,ol); ol=fdot2(A.x,v.w,ol);
        }
        gp[g*4+0][o]=ih+il*LO_SCALE; gp[g*4+1][o]=fh+fl*LO_SCALE;
        gp[g*4+2][o]=gh+gl*LO_SCALE; gp[g*4+3][o]=oh+ol*LO_SCALE;
      }
      __syncthreads();
      // cell (g==0 threads, h = o)
      if (g==0){
        float gi = sigm (gp[0][o]+gp[4][o]+gp[8][o] +gp[12][o]+bcomb[o]);
        float gf = sigm (gp[1][o]+gp[5][o]+gp[9][o] +gp[13][o]+bcomb[256+o]);
        float gg = tanh_(gp[2][o]+gp[6][o]+gp[10][o]+gp[14][o]+bcomb[512+o]);
        float go = sigm (gp[3][o]+gp[7][o]+gp[11][o]+gp[15][o]+bcomb[768+o]);
        float c2 = gf*ct[o] + gi*gg;
        float h2 = go*tanh_(c2);
        ct[o]=c2; ht[o]=h2;
      }
      __syncthreads();
      // S5+S6: APR=relu([ct|ht]); conv (all g, 8 f each, exact f32); wl1 (g==3, o<64)
      if (tid < 128){ uint h,l; pk_hl(fmaxf(ct[2*tid],0.f), fmaxf(ct[2*tid+1],0.f), h,l); APR2[tid]=make_uint2(h,l); }
      else if (tid < 256){ int j=tid-128; uint h,l; pk_hl(fmaxf(ht[2*j],0.f), fmaxf(ht[2*j+1],0.f), h,l); APR2[tid]=make_uint2(h,l); }
      {
        int rb = base & 63;
        const float4* wp = (const float4*)(WcrotF + rb*2048 + gu*8);
        float a0=0.f,a1=0.f,a2=0.f,a3=0.f,a4=0.f,a5=0.f,a6=0.f,a7=0.f;
        #pragma unroll 4
        for (int s=0;s<64;s++){
          float hv = Hf32[s][o];
          float4 wa = wp[s*8];
          float4 wb = wp[s*8+1];
          a0 += hv*wa.x; a1 += hv*wa.y; a2 += hv*wa.z; a3 += hv*wa.w;
          a4 += hv*wb.x; a5 += hv*wb.y; a6 += hv*wb.z; a7 += hv*wb.w;
        }
        int f0 = gu*8;
        cvs[o][f0+0] = fmaxf(a0+bc[f0+0],0.f); cvs[o][f0+1] = fmaxf(a1+bc[f0+1],0.f);
        cvs[o][f0+2] = fmaxf(a2+bc[f0+2],0.f); cvs[o][f0+3] = fmaxf(a3+bc[f0+3],0.f);
        cvs[o][f0+4] = fmaxf(a4+bc[f0+4],0.f); cvs[o][f0+5] = fmaxf(a5+bc[f0+5],0.f);
        cvs[o][f0+6] = fmaxf(a6+bc[f0+6],0.f); cvs[o][f0+7] = fmaxf(a7+bc[f0+7],0.f);
      }
      if (g==3 && o < 64){
        int f = o & 31, kh = o >> 5;          // 2 threads per f, k-halves
        float a=0.f;
        const float* w = Wl1f + f;
        if (kh==0){ for (int k=0;k<256;k++) a += ct[k]*w[k*32]; }
        else      { for (int k=0;k<256;k++) a += ht[k]*w[(256+k)*32]; }
        a += __shfl_xor(a, 32);               // combine halves
        if (kh==0) wv[f] = a + bl1[f];
      }
      __syncthreads();
      // S8: alpha (f32)
      if (tid < 256){
        float s=0.f;
        #pragma unroll
        for (int f=0;f<32;f++) s += cvs[tid][f]*wv[f];
        alpha[tid] = sigm(s);
      }
      __syncthreads();
      // S9+S10 merged: v via in-wave shuffle tree -> APR[256..271]
      // oa = 4og+(oo&3)+32(oo>>2): bank=(4og+f+(oo&3))&31 -> ≤2-way (free); measured 0
      if (tid < 256){
        int f = tid>>3, og = tid&7;
        float s=0.f;
        #pragma unroll 8
        for (int oo=0;oo<32;oo++){
          int oa = 4*og + (oo&3) + 32*(oo>>2);
          s += alpha[oa]*cvs[oa][f];
        }
        s += __shfl_xor(s,1); s += __shfl_xor(s,2); s += __shfl_xor(s,4);  // og-reduce
        float vn = __shfl_xor(s,8);            // partner f^1
        if (og==0 && !(f&1)){
          uint h,l; pk_hl(fmaxf(s,0.f), fmaxf(vn,0.f), h,l);
          APR2[256+(f>>1)]=make_uint2(h,l);
        }
      }
      __syncthreads();
      // S12: Wl2 partials  (g: kpp in [g*34, g*34+34))
      {
        float ahi=0.f, alo=0.f;
        const uint4* wp = Wl24 + (size_t)(g*34)*256 + o;
        const uint4* ap = (const uint4*)(APR2 + g*68);
        #pragma unroll 4
        for (int kpp=0;kpp<34;kpp++){
          uint4 w = wp[0]; wp += 256;
          uint4 A = ap[kpp];
          ahi = fdot2(A.x, w.x, ahi); alo = fdot2(A.y, w.x, alo); alo = fdot2(A.x, w.y, alo);
          ahi = fdot2(A.z, w.z, ahi); alo = fdot2(A.w, w.z, alo); alo = fdot2(A.z, w.w, alo);
        }
        p4[g][o] = ahi + alo*LO_SCALE;
      }
      __syncthreads();
      // S13: APR = [ht raw | nh]; stash nh in alpha[] (dead until next S8)
      if (tid<128){ uint h,l; pk_hl(ht[2*tid], ht[2*tid+1], h,l); APR2[tid]=make_uint2(h,l); }
      else if (tid<256){
        int j=tid-128, o0=2*j, o1=o0+1;
        float n0 = p4[0][o0]+p4[1][o0]+p4[2][o0]+p4[3][o0]+bl2[o0];
        float n1 = p4[0][o1]+p4[1][o1]+p4[2][o1]+p4[3][o1]+bl2[o1];
        uint h,l; pk_hl(n0,n1,h,l); APR2[tid]=make_uint2(h,l);
        alpha[o0] = n0; alpha[o1] = n1;       // nh stash
      }
      __syncthreads();
      // res write (alpha stash) ∥ S14: output partials
      if (l==1 && tid>=128 && tid<256){
        int j=tid-128, o0=2*j, o1=o0+1;
        float* rr = res + (size_t)(t*128+b)*256;
        rr[o0] = alpha[o0]; rr[o1] = alpha[o1];
      }
      {
        float ahi=0.f, alo=0.f;
        const uint4* wp = Wd4 + (size_t)(g*32)*256 + o;
        const uint4* ap = (const uint4*)(APR2 + g*64);
        #pragma unroll 4
        for (int kpp=0;kpp<32;kpp++){
          uint4 w = wp[0]; wp += 256;
          uint4 A = ap[kpp];
          ahi = fdot2(A.x, w.x, ahi); alo = fdot2(A.y, w.x, alo); alo = fdot2(A.x, w.y, alo);
          ahi = fdot2(A.z, w.z, ahi); alo = fdot2(A.w, w.z, alo); alo = fdot2(A.z, w.w, alo);
        }
        p4[g][o] = ahi + alo*LO_SCALE;
      }
      __syncthreads();
      // S15: Hbuf ring append relu(output) f32; next xi (output for l=0, xcon[t+1] for l=1)
      if (tid<128){
        int o0=2*tid, o1=o0+1;
        float u0 = p4[0][o0]+p4[1][o0]+p4[2][o0]+p4[3][o0]+bd[o0];
        float u1 = p4[0][o1]+p4[1][o1]+p4[2][o1]+p4[3][o1]+bd[o1];
        int s = base & 63;
        Hf32[s][o0] = fmaxf(u0,0.f);
        Hf32[s][o1] = fmaxf(u1,0.f);
        if (l==0){
          uint h,lw; pk_hl(u0, u1, h, lw);
          APR2[tid]=make_uint2(h,lw);
        } else if (t < 63){
          const float* xr = xcon + (size_t)(b*64+t+1)*256;
          uint h,lw; pk_hl(xr[o0], xr[o1], h, lw);
          APR2[tid]=make_uint2(h,lw);
        }
      }
      __syncthreads();
      base++;
    }
  }
}

// ---------- K3: out[b,c,h,t] = relu(res[t,b,h])*wend[c] + bend[c]  (float32) ----------
__global__ void k3(const float* __restrict__ res, const float* __restrict__ wend,
                   const float* __restrict__ bend, float* __restrict__ out)
{
  __shared__ float r2[64][257];
  int b = blockIdx.x, tid = threadIdx.x;
  for (int i = tid; i < 16384; i += 256){
    int t = i >> 8, h = i & 255;
    r2[t][h] = fmaxf(res[(size_t)(t*128+b)*256 + h], 0.f);
  }
  __syncthreads();
  int tt = tid & 63, hg = tid >> 6;
  for (int c=0;c<8;c++){
    float we = wend[c], be = bend[c];
    for (int hh=0;hh<64;hh++){
      int h = hg*64 + hh;
      out[((size_t)(b*8+c)*256 + h)*64 + tt] = r2[tt][h]*we + be;
    }
  }
}

// ---------- launch ----------
extern "C" __attribute__((visibility("default"), used))
void kernel_launch(void* const* d_in, const int* in_sizes, int n_in,
                   void* d_out, int out_size, void* d_ws, size_t ws_size,
                   hipStream_t stream)
{
  const float* x    = (const float*)d_in[0];
  const float* wst  = (const float*)d_in[1];
  const float* bst  = (const float*)d_in[2];
  const float* Wh   = (const float*)d_in[3];
  const float* bh   = (const float*)d_in[4];
  const float* Wih  = (const float*)d_in[5];
  const float* Whh  = (const float*)d_in[6];
  const float* bih  = (const float*)d_in[7];
  const float* bhh  = (const float*)d_in[8];
  const float* Wd   = (const float*)d_in[9];
  const float* bd   = (const float*)d_in[10];
  const float* Wc   = (const float*)d_in[11];
  const float* bc   = (const float*)d_in[12];
  const float* Wl1  = (const float*)d_in[13];
  const float* bl1  = (const float*)d_in[14];
  const float* Wl2  = (const float*)d_in[15];
  const float* bl2  = (const float*)d_in[16];
  const float* wend = (const float*)d_in[17];
  const float* bend = (const float*)d_in[18];

  char* ws = (char*)d_ws;
  uint4* Wd4    = (uint4*)(ws + 0);          // 524288 B
  uint4* Wc4hi  = (uint4*)(ws + 524288);     // 1048576 B
  uint4* Wc4lo  = (uint4*)(ws + 1572864);    // 1048576 B
  uint4* Wl24   = (uint4*)(ws + 2621440);    // 557056 B
  float* Wl1f   = (float*)(ws + 3178496);    // 65536 B
  float* WcrotF = (float*)(ws + 3244032);    // 524288 B
  uint*  WhT2   = (uint*) (ws + 3768320);    // 131072 B
  float* bcomb  = (float*)(ws + 3899392);    // 4096 B
  ushort* yT    = (ushort*)(ws + 3903488);   // 4194304 B
  float* xcon   = (float*)(ws + 8097792);    // 8388608 B
  float* res    = (float*)(ws + 16486400);   // 8388608 B -> end 24875008

  kPack<<<512, 256, 0, stream>>>(Wd, Wih, Whh, Wl1, Wl2, Wc, Wh, bih, bhh,
                                 Wd4, Wc4hi, Wc4lo, Wl24, Wl1f, WcrotF, WhT2, bcomb);
  k1a<<<dim3(128,4), 256, 0, stream>>>(x, wst, bst, yT);
  k1b<<<128, 256, 0, stream>>>((const uint*)yT, WhT2, bh, xcon);
  TPALSTM_17205638987874_kernel<<<128, 1024, 0, stream>>>(xcon, Wd4, Wc4hi, Wc4lo, Wl24,
                                                          Wl1f, WcrotF,
                                                          bd, bcomb, bl1, bl2, bc, res);
  k3<<<128, 256, 0, stream>>>(res, wend, bend, (float*)d_out);
}

// Round 21
// 4835.807 us; speedup vs baseline: 2.0804x; 1.0114x over previous
//
#include <hip/hip_runtime.h>
#include <hip/hip_bf16.h>

typedef unsigned int uint;
typedef unsigned short ushort;
typedef __fp16 half2_t __attribute__((ext_vector_type(2)));

// ---------- helpers ----------
__device__ __forceinline__ ushort f16b(float x){
  return __builtin_bit_cast(ushort, (_Float16)x);   // RNE
}
__device__ __forceinline__ uint pk_rne(float a, float b){
  return (uint)f16b(a) | ((uint)f16b(b) << 16);
}
// hi/lo double-f16 split; lo scaled by 2^11 (stays f16-normal; avoids dot2 FTZ).
// value = hi + lo * 2^-11
__device__ __forceinline__ void pk_hl(float a, float b, uint& h, uint& l){
  _Float16 ha = (_Float16)a, hb = (_Float16)b;      // RNE
  float la = (a - (float)ha) * 2048.f;
  float lb = (b - (float)hb) * 2048.f;
  h = (uint)__builtin_bit_cast(ushort, ha) | ((uint)__builtin_bit_cast(ushort, hb) << 16);
  l = pk_rne(la, lb);
}
__device__ __forceinline__ float fdot2(uint a, uint b, float c){
#if __has_builtin(__builtin_amdgcn_fdot2)
  return __builtin_amdgcn_fdot2(__builtin_bit_cast(half2_t, a),
                                __builtin_bit_cast(half2_t, b), c, false);
#else
  half2_t ha = __builtin_bit_cast(half2_t, a), hb = __builtin_bit_cast(half2_t, b);
  return c + (float)ha.x*(float)hb.x + (float)ha.y*(float)hb.y;
#endif
}
__device__ __forceinline__ float sigm(float x){ return 1.0f/(1.0f+__expf(-x)); }
__device__ __forceinline__ float tanh_(float x){
  x = fminf(fmaxf(x, -15.f), 15.f);
  float e = __expf(-2.f*x);
  return (1.f-e)/(1.f+e);
}
#define LO_SCALE (1.0f/2048.0f)

// B=128, C=8, N=256, T=64, Hd=256, L=2, F=32 ; OUTPUT = float32

// ---------- kPack ----------
// Wd2   [128 kpp][256 o] uint2 {hi(k0,k1), hi(k2,k3)}  k=[xi|attn]  (f16-hi only)
// Wc4hi [256 kp][256 h]  uint4 gate-hi ; Wc4lo gate-lo (kept full hi/lo — recurrence-critical)
// Wl22  [136 kpp][256 o] uint2 like Wd2                k=relu([ct|ht|v]) (544)
// Wl1f [512][32] f32 ; WcrotF [64 rb][64 s][32 f] f32 (ring-rotated) ; WhT2 [128][256]
__global__ void kPack(const float* __restrict__ Wd, const float* __restrict__ Wih,
                      const float* __restrict__ Whh, const float* __restrict__ Wl1,
                      const float* __restrict__ Wl2, const float* __restrict__ Wc,
                      const float* __restrict__ Wh,  const float* __restrict__ bih,
                      const float* __restrict__ bhh,
                      uint2* __restrict__ Wd2, uint4* __restrict__ Wc4hi,
                      uint4* __restrict__ Wc4lo, uint2* __restrict__ Wl22,
                      float* __restrict__ Wl1f, float* __restrict__ WcrotF,
                      uint* __restrict__ WhT2, float* __restrict__ bcomb)
{
  const int NTOT = 32768 + 65536 + 34816 + 16384 + 131072 + 32768 + 1024;
  for (int idx = blockIdx.x*blockDim.x + threadIdx.x; idx < NTOT; idx += gridDim.x*blockDim.x){
    int i = idx;
    if (i < 32768){
      int kpp=i>>8, o=i&255, k0=4*kpp;
      Wd2[i] = make_uint2(pk_rne(Wd[o*512+k0],   Wd[o*512+k0+1]),
                          pk_rne(Wd[o*512+k0+2], Wd[o*512+k0+3]));
      continue; }
    i -= 32768;
    if (i < 65536){
      int kp=i>>8, hh=i&255;
      uint wh[4], wl[4];
      #pragma unroll
      for (int gi=0; gi<4; gi++){
        int row = gi*256+hh;
        float a,b;
        if (kp<128){ a=Wih[row*256+2*kp]; b=Wih[row*256+2*kp+1]; }
        else       { a=Whh[row*256+2*(kp-128)]; b=Whh[row*256+2*(kp-128)+1]; }
        pk_hl(a,b,wh[gi],wl[gi]);
      }
      Wc4hi[i] = make_uint4(wh[0],wh[1],wh[2],wh[3]);
      Wc4lo[i] = make_uint4(wl[0],wl[1],wl[2],wl[3]); continue; }
    i -= 65536;
    if (i < 34816){
      int kpp=i>>8, o=i&255, k0=4*kpp;
      Wl22[i] = make_uint2(pk_rne(Wl2[o*544+k0],   Wl2[o*544+k0+1]),
                           pk_rne(Wl2[o*544+k0+2], Wl2[o*544+k0+3]));
      continue; }
    i -= 34816;
    if (i < 16384){ int kk=i>>5, f=i&31; Wl1f[i] = Wl1[f*512+kk]; continue; }
    i -= 16384;
    if (i < 131072){ int rb=i>>11, r=i&2047, s=r>>5, f=r&31;
      WcrotF[i] = Wc[f*64 + ((s - rb) & 63)]; continue; }
    i -= 131072;
    if (i < 32768){ int np=i>>8, h=i&255;
      WhT2[i] = pk_rne(Wh[h*256+2*np], Wh[h*256+2*np+1]); continue; }
    i -= 32768;
    bcomb[i] = bih[i] + bhh[i];
  }
}

// ---------- K1a ----------
__global__ void k1a(const float* __restrict__ x, const float* __restrict__ wst,
                    const float* __restrict__ bst, ushort* __restrict__ yT)
{
  int b = blockIdx.x, tq = blockIdx.y, n = threadIdx.x;
  float acc[16];
  #pragma unroll
  for (int k=0;k<16;k++) acc[k]=0.f;
  for (int c=0;c<8;c++){
    const float4* xp = (const float4*)(x + ((size_t)((b*8+c)*256 + n)*64 + tq*16));
    float wc = wst[c];
    #pragma unroll
    for (int q=0;q<4;q++){
      float4 v = xp[q];
      acc[4*q+0] += v.x*wc; acc[4*q+1] += v.y*wc;
      acc[4*q+2] += v.z*wc; acc[4*q+3] += v.w*wc;
    }
  }
  float b0 = bst[0];
  #pragma unroll
  for (int k=0;k<16;k++){
    float v = fmaxf(acc[k]+b0, 0.f);
    yT[(size_t)(b*64 + tq*16 + k)*256 + n] = f16b(v);
  }
}

// ---------- K1b ----------
__global__ void k1b(const uint* __restrict__ yT2, const uint* __restrict__ WhT2,
                    const float* __restrict__ bh, float* __restrict__ xcon)
{
  __shared__ uint yp[8192];
  int b = blockIdx.x, tid = threadIdx.x;
  for (int i = tid; i < 8192; i += 256) yp[i] = yT2[(size_t)b*8192 + i];
  __syncthreads();
  int h = tid;
  float bias = bh[h];
  for (int tq=0;tq<4;tq++){
    float acc[16];
    #pragma unroll
    for (int k=0;k<16;k++) acc[k]=0.f;
    for (int np=0;np<128;np++){
      uint w2 = WhT2[np*256 + h];
      #pragma unroll
      for (int k=0;k<16;k++)
        acc[k] = fdot2(yp[(tq*16+k)*128 + np], w2, acc[k]);
    }
    #pragma unroll
    for (int k=0;k<16;k++)
      xcon[(size_t)(b*64 + tq*16 + k)*256 + h] = fmaxf(acc[k]+bias, 0.f);
  }
}

// ---------- K2: scan — 1024 threads, 4-way k-split, exact-f32 attention ----------
// Wd/Wl2 GEMVs: f16-hi weights, hi/lo activations (act-lo cross term kept):
//   w·x ≈ wh·xh + wh·xl/2048  (dropped: wl·xh ~ weight residual only)
__global__ __launch_bounds__(1024, 1)
void TPALSTM_17205638987874_kernel(const float* __restrict__ xcon,
        const uint2* __restrict__ Wd2, const uint4* __restrict__ Wc4hi,
        const uint4* __restrict__ Wc4lo, const uint2* __restrict__ Wl22,
        const float* __restrict__ Wl1f, const float* __restrict__ WcrotF,
        const float* __restrict__ bd, const float* __restrict__ bcomb,
        const float* __restrict__ bl1, const float* __restrict__ bl2,
        const float* __restrict__ bc, float* __restrict__ res)
{
  __shared__ float Hf32[64][256];          // Hbuf ring, f32 (phys slot s = base&63)
  __shared__ float cvs[256][33];           // cv f32 [o][f] (+1 pad)
  __shared__ float gp[16][256];            // gate partials
  __shared__ float p4[4][256];             // 4-way GEMV partials
  __shared__ float ht[256], ct[256], alpha[256];  // alpha doubles as nh-stash
  __shared__ __align__(16) uint2 APR2[288];// {hi, lo_scaled} per k-pair
  __shared__ float wv[32];                 // wl1 result, f32

  int b = blockIdx.x, tid = threadIdx.x;
  int g = tid >> 8, o = tid & 255;
  int gu = __builtin_amdgcn_readfirstlane(g);   // wave-uniform group id (SGPR)

  for (int i = tid; i < 64*256; i += 1024) ((float*)Hf32)[i] = 0.f;
  if (tid < 256){ ht[tid]=0.f; ct[tid]=0.f; }
  if (tid >= 128 && tid < 256) APR2[tid] = make_uint2(0u,0u);  // attn_out = 0
  if (tid < 128){                                              // t=0 xi
    const float* xr = xcon + (size_t)(b*64+0)*256;
    uint h,l; pk_hl(xr[2*tid], xr[2*tid+1], h, l);
    APR2[tid] = make_uint2(h,l);
  }
  __syncthreads();

  int base = 0;
  for (int t=0;t<64;t++){
    for (int l=0;l<2;l++){
      // S2: xd partials  (g: kpp in [g*32, g*32+32))
      {
        float ahi=0.f, alo=0.f;
        const uint2* wp = Wd2 + (size_t)(g*32)*256 + o;
        const uint4* ap = (const uint4*)(APR2 + g*64);
        #pragma unroll 4
        for (int kpp=0;kpp<32;kpp++){
          uint2 w = wp[0]; wp += 256;
          uint4 A = ap[kpp];
          ahi = fdot2(A.x, w.x, ahi); alo = fdot2(A.y, w.x, alo);
          ahi = fdot2(A.z, w.y, ahi); alo = fdot2(A.w, w.y, alo);
        }
        p4[g][o] = ahi + alo*LO_SCALE;
      }
      __syncthreads();
      // S3: APR = [xd | ht raw]
      if (tid < 128){
        int o0=2*tid, o1=o0+1;
        float x0 = p4[0][o0]+p4[1][o0]+p4[2][o0]+p4[3][o0]+bd[o0];
        float x1 = p4[0][o1]+p4[1][o1]+p4[2][o1]+p4[3][o1]+bd[o1];
        uint h,l; pk_hl(x0,x1,h,l); APR2[tid]=make_uint2(h,l);
      } else if (tid < 256){
        int j=tid-128; uint h,l; pk_hl(ht[2*j], ht[2*j+1], h, l); APR2[tid]=make_uint2(h,l);
      }
      __syncthreads();
      // S4: gate partials  (g: kp in [g*64, g*64+64)) — full hi/lo (recurrence-critical)
      {
        float ih=0.f,il=0.f,fh=0.f,fl=0.f,gh=0.f,gl=0.f,oh=0.f,ol=0.f;
        const uint4* whp = Wc4hi + (size_t)(g*64)*256 + o;
        const uint4* wlp = Wc4lo + (size_t)(g*64)*256 + o;
        #pragma unroll 4
        for (int kp=g*64; kp<g*64+64; kp++){
          uint4 w = whp[0]; whp += 256;
          uint4 v = wlp[0]; wlp += 256;
          uint2 A = APR2[kp];
          ih=fdot2(A.x,w.x,ih); il=fdot2(A.y,w.x,il); il=fdot2(A.x,v.x,il);
          fh=fdot2(A.x,w.y,fh); fl=fdot2(A.y,w.y,fl); fl=fdot2(A.x,v.y,fl);
          gh=fdot2(A.x,w.z,gh); gl=fdot2(A.y,w.z,gl); gl=fdot2(A.x,v.z,gl);
          oh=fdot2(A.x,w.w,oh); ol=fdot2(A.y,w.w,ol); ol=fdot2(A.x,v.w,ol);
        }
        gp[g*4+0][o]=ih+il*LO_SCALE; gp[g*4+1][o]=fh+fl*LO_SCALE;
        gp[g*4+2][o]=gh+gl*LO_SCALE; gp[g*4+3][o]=oh+ol*LO_SCALE;
      }
      __syncthreads();
      // cell (g==0 threads, h = o)
      if (g==0){
        float gi = sigm (gp[0][o]+gp[4][o]+gp[8][o] +gp[12][o]+bcomb[o]);
        float gf = sigm (gp[1][o]+gp[5][o]+gp[9][o] +gp[13][o]+bcomb[256+o]);
        float gg = tanh_(gp[2][o]+gp[6][o]+gp[10][o]+gp[14][o]+bcomb[512+o]);
        float go = sigm (gp[3][o]+gp[7][o]+gp[11][o]+gp[15][o]+bcomb[768+o]);
        float c2 = gf*ct[o] + gi*gg;
        float h2 = go*tanh_(c2);
        ct[o]=c2; ht[o]=h2;
      }
      __syncthreads();
      // S5+S6: APR=relu([ct|ht]); conv (all g, 8 f each, exact f32); wl1 (g==3, o<64)
      if (tid < 128){ uint h,l; pk_hl(fmaxf(ct[2*tid],0.f), fmaxf(ct[2*tid+1],0.f), h,l); APR2[tid]=make_uint2(h,l); }
      else if (tid < 256){ int j=tid-128; uint h,l; pk_hl(fmaxf(ht[2*j],0.f), fmaxf(ht[2*j+1],0.f), h,l); APR2[tid]=make_uint2(h,l); }
      {
        int rb = base & 63;
        const float4* wp = (const float4*)(WcrotF + rb*2048 + gu*8);
        float a0=0.f,a1=0.f,a2=0.f,a3=0.f,a4=0.f,a5=0.f,a6=0.f,a7=0.f;
        #pragma unroll 4
        for (int s=0;s<64;s++){
          float hv = Hf32[s][o];
          float4 wa = wp[s*8];
          float4 wb = wp[s*8+1];
          a0 += hv*wa.x; a1 += hv*wa.y; a2 += hv*wa.z; a3 += hv*wa.w;
          a4 += hv*wb.x; a5 += hv*wb.y; a6 += hv*wb.z; a7 += hv*wb.w;
        }
        int f0 = gu*8;
        cvs[o][f0+0] = fmaxf(a0+bc[f0+0],0.f); cvs[o][f0+1] = fmaxf(a1+bc[f0+1],0.f);
        cvs[o][f0+2] = fmaxf(a2+bc[f0+2],0.f); cvs[o][f0+3] = fmaxf(a3+bc[f0+3],0.f);
        cvs[o][f0+4] = fmaxf(a4+bc[f0+4],0.f); cvs[o][f0+5] = fmaxf(a5+bc[f0+5],0.f);
        cvs[o][f0+6] = fmaxf(a6+bc[f0+6],0.f); cvs[o][f0+7] = fmaxf(a7+bc[f0+7],0.f);
      }
      if (g==3 && o < 64){
        int f = o & 31, kh = o >> 5;          // 2 threads per f, k-halves
        float a=0.f;
        const float* w = Wl1f + f;
        if (kh==0){ for (int k=0;k<256;k++) a += ct[k]*w[k*32]; }
        else      { for (int k=0;k<256;k++) a += ht[k]*w[(256+k)*32]; }
        a += __shfl_xor(a, 32);               // combine halves
        if (kh==0) wv[f] = a + bl1[f];
      }
      __syncthreads();
      // S8: alpha (f32)
      if (tid < 256){
        float s=0.f;
        #pragma unroll
        for (int f=0;f<32;f++) s += cvs[tid][f]*wv[f];
        alpha[tid] = sigm(s);
      }
      __syncthreads();
      // S9+S10 merged: v via in-wave shuffle tree -> APR[256..271]
      // oa = 4og+(oo&3)+32(oo>>2): ≤2-way banks (free); measured 0 conflicts
      if (tid < 256){
        int f = tid>>3, og = tid&7;
        float s=0.f;
        #pragma unroll 8
        for (int oo=0;oo<32;oo++){
          int oa = 4*og + (oo&3) + 32*(oo>>2);
          s += alpha[oa]*cvs[oa][f];
        }
        s += __shfl_xor(s,1); s += __shfl_xor(s,2); s += __shfl_xor(s,4);  // og-reduce
        float vn = __shfl_xor(s,8);            // partner f^1
        if (og==0 && !(f&1)){
          uint h,l; pk_hl(fmaxf(s,0.f), fmaxf(vn,0.f), h,l);
          APR2[256+(f>>1)]=make_uint2(h,l);
        }
      }
      __syncthreads();
      // S12: Wl2 partials  (g: kpp in [g*34, g*34+34))
      {
        float ahi=0.f, alo=0.f;
        const uint2* wp = Wl22 + (size_t)(g*34)*256 + o;
        const uint4* ap = (const uint4*)(APR2 + g*68);
        #pragma unroll 4
        for (int kpp=0;kpp<34;kpp++){
          uint2 w = wp[0]; wp += 256;
          uint4 A = ap[kpp];
          ahi = fdot2(A.x, w.x, ahi); alo = fdot2(A.y, w.x, alo);
          ahi = fdot2(A.z, w.y, ahi); alo = fdot2(A.w, w.y, alo);
        }
        p4[g][o] = ahi + alo*LO_SCALE;
      }
      __syncthreads();
      // S13: APR = [ht raw | nh]; stash nh in alpha[] (dead until next S8)
      if (tid<128){ uint h,l; pk_hl(ht[2*tid], ht[2*tid+1], h,l); APR2[tid]=make_uint2(h,l); }
      else if (tid<256){
        int j=tid-128, o0=2*j, o1=o0+1;
        float n0 = p4[0][o0]+p4[1][o0]+p4[2][o0]+p4[3][o0]+bl2[o0];
        float n1 = p4[0][o1]+p4[1][o1]+p4[2][o1]+p4[3][o1]+bl2[o1];
        uint h,l; pk_hl(n0,n1,h,l); APR2[tid]=make_uint2(h,l);
        alpha[o0] = n0; alpha[o1] = n1;       // nh stash
      }
      __syncthreads();
      // res write (alpha stash) ∥ S14: output partials (Wd2 stream)
      if (l==1 && tid>=128 && tid<256){
        int j=tid-128, o0=2*j, o1=o0+1;
        float* rr = res + (size_t)(t*128+b)*256;
        rr[o0] = alpha[o0]; rr[o1] = alpha[o1];
      }
      {
        float ahi=0.f, alo=0.f;
        const uint2* wp = Wd2 + (size_t)(g*32)*256 + o;
        const uint4* ap = (const uint4*)(APR2 + g*64);
        #pragma unroll 4
        for (int kpp=0;kpp<32;kpp++){
          uint2 w = wp[0]; wp += 256;
          uint4 A = ap[kpp];
          ahi = fdot2(A.x, w.x, ahi); alo = fdot2(A.y, w.x, alo);
          ahi = fdot2(A.z, w.y, ahi); alo = fdot2(A.w, w.y, alo);
        }
        p4[g][o] = ahi + alo*LO_SCALE;
      }
      __syncthreads();
      // S15: Hbuf ring append relu(output) f32; next xi (output for l=0, xcon[t+1] for l=1)
      if (tid<128){
        int o0=2*tid, o1=o0+1;
        float u0 = p4[0][o0]+p4[1][o0]+p4[2][o0]+p4[3][o0]+bd[o0];
        float u1 = p4[0][o1]+p4[1][o1]+p4[2][o1]+p4[3][o1]+bd[o1];
        int s = base & 63;
        Hf32[s][o0] = fmaxf(u0,0.f);
        Hf32[s][o1] = fmaxf(u1,0.f);
        if (l==0){
          uint h,lw; pk_hl(u0, u1, h, lw);
          APR2[tid]=make_uint2(h,lw);
        } else if (t < 63){
          const float* xr = xcon + (size_t)(b*64+t+1)*256;
          uint h,lw; pk_hl(xr[o0], xr[o1], h, lw);
          APR2[tid]=make_uint2(h,lw);
        }
      }
      __syncthreads();
      base++;
    }
  }
}

// ---------- K3: out[b,c,h,t] = relu(res[t,b,h])*wend[c] + bend[c]  (float32) ----------
__global__ void k3(const float* __restrict__ res, const float* __restrict__ wend,
                   const float* __restrict__ bend, float* __restrict__ out)
{
  __shared__ float r2[64][257];
  int b = blockIdx.x, tid = threadIdx.x;
  for (int i = tid; i < 16384; i += 256){
    int t = i >> 8, h = i & 255;
    r2[t][h] = fmaxf(res[(size_t)(t*128+b)*256 + h], 0.f);
  }
  __syncthreads();
  int tt = tid & 63, hg = tid >> 6;
  for (int c=0;c<8;c++){
    float we = wend[c], be = bend[c];
    for (int hh=0;hh<64;hh++){
      int h = hg*64 + hh;
      out[((size_t)(b*8+c)*256 + h)*64 + tt] = r2[tt][h]*we + be;
    }
  }
}

// ---------- launch ----------
extern "C" __attribute__((visibility("default"), used))
void kernel_launch(void* const* d_in, const int* in_sizes, int n_in,
                   void* d_out, int out_size, void* d_ws, size_t ws_size,
                   hipStream_t stream)
{
  const float* x    = (const float*)d_in[0];
  const float* wst  = (const float*)d_in[1];
  const float* bst  = (const float*)d_in[2];
  const float* Wh   = (const float*)d_in[3];
  const float* bh   = (const float*)d_in[4];
  const float* Wih  = (const float*)d_in[5];
  const float* Whh  = (const float*)d_in[6];
  const float* bih  = (const float*)d_in[7];
  const float* bhh  = (const float*)d_in[8];
  const float* Wd   = (const float*)d_in[9];
  const float* bd   = (const float*)d_in[10];
  const float* Wc   = (const float*)d_in[11];
  const float* bc   = (const float*)d_in[12];
  const float* Wl1  = (const float*)d_in[13];
  const float* bl1  = (const float*)d_in[14];
  const float* Wl2  = (const float*)d_in[15];
  const float* bl2  = (const float*)d_in[16];
  const float* wend = (const float*)d_in[17];
  const float* bend = (const float*)d_in[18];

  char* ws = (char*)d_ws;
  uint2* Wd2    = (uint2*)(ws + 0);          // 262144 B
  uint4* Wc4hi  = (uint4*)(ws + 262144);     // 1048576 B
  uint4* Wc4lo  = (uint4*)(ws + 1310720);    // 1048576 B
  uint2* Wl22   = (uint2*)(ws + 2359296);    // 278528 B
  float* Wl1f   = (float*)(ws + 2637824);    // 65536 B
  float* WcrotF = (float*)(ws + 2703360);    // 524288 B
  uint*  WhT2   = (uint*) (ws + 3227648);    // 131072 B
  float* bcomb  = (float*)(ws + 3358720);    // 4096 B
  ushort* yT    = (ushort*)(ws + 3362816);   // 4194304 B
  float* xcon   = (float*)(ws + 7557120);    // 8388608 B
  float* res    = (float*)(ws + 15945728);   // 8388608 B -> end 24334336

  kPack<<<512, 256, 0, stream>>>(Wd, Wih, Whh, Wl1, Wl2, Wc, Wh, bih, bhh,
                                 Wd2, Wc4hi, Wc4lo, Wl22, Wl1f, WcrotF, WhT2, bcomb);
  k1a<<<dim3(128,4), 256, 0, stream>>>(x, wst, bst, yT);
  k1b<<<128, 256, 0, stream>>>((const uint*)yT, WhT2, bh, xcon);
  TPALSTM_17205638987874_kernel<<<128, 1024, 0, stream>>>(xcon, Wd2, Wc4hi, Wc4lo, Wl22,
                                                          Wl1f, WcrotF,
                                                          bd, bcomb, bl1, bl2, bc, res);
  k3<<<128, 256, 0, stream>>>(res, wend, bend, (float*)d_out);
}